// Round 2
// baseline (2886.814 us; speedup 1.0000x reference)
//
#include <hip/hip_runtime.h>
#include <math.h>

#define SLOPE  0.2f
#define LN_EPS 1e-5f
#define HID    64
#define IN_DIM 128
#define BM     64        // rows per proj block

// ---------- K1: tiled fused projections: xl=x@Wl+bl, xr=x@Wr+br, res=x@Wres ----------
// 256 threads; thread t: col-base cb=(t&15)*4 in each of the 3 output matrices,
// rows ry=(t>>4)*4 .. +3. x tile staged in padded LDS; W streamed from L1/L2.
__global__ __launch_bounds__(256) void proj_kernel(
    const float* __restrict__ x,
    const float* __restrict__ Wl, const float* __restrict__ bl,
    const float* __restrict__ Wr, const float* __restrict__ br,
    const float* __restrict__ Wres,
    float* __restrict__ xl, float* __restrict__ xr, float* __restrict__ out_un,
    int n)
{
    __shared__ float xs[BM][132];            // +4 pad: 4-row stride = 528 dw = 16 mod 32 banks
    int t = threadIdx.x;
    int row0 = blockIdx.x * BM;

    // stage x tile: 2048 float4, 8 per thread
#pragma unroll
    for (int p = 0; p < 8; ++p) {
        int f  = t + p * 256;
        int r  = f >> 5;                     // 32 float4 per row
        int c4 = f & 31;
        float4 v = make_float4(0.f, 0.f, 0.f, 0.f);
        if (row0 + r < n) v = ((const float4*)x)[(long)(row0 + r) * 32 + c4];
        *(float4*)&xs[r][c4 * 4] = v;
    }
    __syncthreads();

    int cb = (t & 15) * 4;
    int ry = (t >> 4) * 4;

    float4 acc[3][4];
#pragma unroll
    for (int r = 0; r < 4; ++r) {
        acc[0][r] = *(const float4*)&bl[cb];
        acc[1][r] = *(const float4*)&br[cb];
        acc[2][r] = make_float4(0.f, 0.f, 0.f, 0.f);
    }

    for (int k4 = 0; k4 < 32; ++k4) {
        float4 xv[4];
#pragma unroll
        for (int r = 0; r < 4; ++r)
            xv[r] = *(const float4*)&xs[ry + r][k4 * 4];
#pragma unroll
        for (int kk = 0; kk < 4; ++kk) {
            int k = k4 * 4 + kk;
            float4 w0 = *(const float4*)&Wl  [k * HID + cb];
            float4 w1 = *(const float4*)&Wr  [k * HID + cb];
            float4 w2 = *(const float4*)&Wres[k * HID + cb];
#pragma unroll
            for (int r = 0; r < 4; ++r) {
                float xvk = (kk == 0) ? xv[r].x : (kk == 1) ? xv[r].y
                          : (kk == 2) ? xv[r].z : xv[r].w;
                acc[0][r].x = fmaf(xvk, w0.x, acc[0][r].x);
                acc[0][r].y = fmaf(xvk, w0.y, acc[0][r].y);
                acc[0][r].z = fmaf(xvk, w0.z, acc[0][r].z);
                acc[0][r].w = fmaf(xvk, w0.w, acc[0][r].w);
                acc[1][r].x = fmaf(xvk, w1.x, acc[1][r].x);
                acc[1][r].y = fmaf(xvk, w1.y, acc[1][r].y);
                acc[1][r].z = fmaf(xvk, w1.z, acc[1][r].z);
                acc[1][r].w = fmaf(xvk, w1.w, acc[1][r].w);
                acc[2][r].x = fmaf(xvk, w2.x, acc[2][r].x);
                acc[2][r].y = fmaf(xvk, w2.y, acc[2][r].y);
                acc[2][r].z = fmaf(xvk, w2.z, acc[2][r].z);
                acc[2][r].w = fmaf(xvk, w2.w, acc[2][r].w);
            }
        }
    }

#pragma unroll
    for (int r = 0; r < 4; ++r) {
        long ro = row0 + ry + r;
        if (ro < n) {
            *(float4*)&xl    [ro * HID + cb] = acc[0][r];
            *(float4*)&xr    [ro * HID + cb] = acc[1][r];
            *(float4*)&out_un[ro * HID + cb] = acc[2][r];
        }
    }
}

// ---------- K2: degree init (self-loop counts as 1) ----------
__global__ void deg_init_kernel(int* __restrict__ deg, int n) {
    for (int i = blockIdx.x * blockDim.x + threadIdx.x; i < n; i += gridDim.x * blockDim.x)
        deg[i] = 1;
}

// ---------- K3: degree histogram over real edges ----------
__global__ void deg_count_kernel(const int* __restrict__ dst, int* __restrict__ deg, int e) {
    for (int i = blockIdx.x * blockDim.x + threadIdx.x; i < e; i += gridDim.x * blockDim.x)
        atomicAdd(&deg[dst[i]], 1);
}

// ---------- K4: single-block exclusive scan, int4 per thread (4096/chunk) ----------
__global__ __launch_bounds__(1024) void scan_kernel(
    const int* __restrict__ deg, int* __restrict__ off, int* __restrict__ cursor, int n)
{
    __shared__ int wsum[16];
    __shared__ int carry_s;
    int t = threadIdx.x, lane = t & 63, w = t >> 6;
    if (t == 0) carry_s = 0;
    __syncthreads();
    for (int base = 0; base < n; base += 4096) {
        int i0 = base + t * 4;
        int4 v = make_int4(0, 0, 0, 0);
        if (i0 + 3 < n)      v = *(const int4*)&deg[i0];
        else if (i0 < n) {
            v.x = deg[i0];
            if (i0 + 1 < n) v.y = deg[i0 + 1];
            if (i0 + 2 < n) v.z = deg[i0 + 2];
        }
        int local = v.x + v.y + v.z + v.w;
        int inc = local;
#pragma unroll
        for (int d = 1; d < 64; d <<= 1) {
            int o = __shfl_up(inc, d, 64);
            if (lane >= d) inc += o;
        }
        if (lane == 63) wsum[w] = inc;
        __syncthreads();
        if (w == 0 && lane < 16) {
            int s = wsum[lane];
#pragma unroll
            for (int d = 1; d < 16; d <<= 1) {
                int o = __shfl_up(s, d, 16);
                if (lane >= d) s += o;
            }
            wsum[lane] = s;
        }
        __syncthreads();
        int woff = (w > 0) ? wsum[w - 1] : 0;
        int bc = carry_s;
        __syncthreads();                       // reads of carry_s/wsum done
        int o0 = bc + woff + inc - local;      // exclusive prefix of this thread's 4
        int o1 = o0 + v.x, o2 = o1 + v.y, o3 = o2 + v.z;
        if (i0     < n) { off[i0]     = o0; cursor[i0]     = o0; }
        if (i0 + 1 < n) { off[i0 + 1] = o1; cursor[i0 + 1] = o1; }
        if (i0 + 2 < n) { off[i0 + 2] = o2; cursor[i0 + 2] = o2; }
        if (i0 + 3 < n) { off[i0 + 3] = o3; cursor[i0 + 3] = o3; }
        if (t == 1023) carry_s = bc + wsum[15];
        __syncthreads();                       // carry visible; wsum free
    }
    if (threadIdx.x == 0) off[n] = carry_s;
}

// ---------- K5: scatter edges (and self-loops) into CSR by dst ----------
__global__ void scatter_kernel(const int* __restrict__ src, const int* __restrict__ dst,
                               int* __restrict__ cursor, int* __restrict__ csr,
                               int e, int n)
{
    int total = e + n;
    for (int i = blockIdx.x * blockDim.x + threadIdx.x; i < total; i += gridDim.x * blockDim.x) {
        int d, s;
        if (i < e) { d = dst[i]; s = src[i]; }
        else       { d = i - e;  s = i - e; }   // self-loop
        int p = atomicAdd(&cursor[d], 1);
        csr[p] = s;
    }
}

__global__ void init_red_kernel(double* red) {
    red[0] = 0.0; red[1] = 0.0;
}

// ---------- K6: per-node attention, one wave per node, lane=(h*16+c), 4-deep MLP ----------
__global__ __launch_bounds__(256) void attn_kernel(
    const float* __restrict__ xl, const float* __restrict__ xr,
    const float* __restrict__ att, const float* __restrict__ bias,
    const int* __restrict__ off, const int* __restrict__ csr,
    float* __restrict__ out_un,   // holds x@W_res on entry; overwritten with row result
    double* __restrict__ red, int n)
{
    int lane = threadIdx.x & 63;
    int node = blockIdx.x * 4 + (threadIdx.x >> 6);
    if (node >= n) return;

    float a    = att[lane];
    float bi   = bias[lane];
    float xr_v = xr[(long)node * HID + lane];

    int e0 = off[node], e1 = off[node + 1];

    float m = -INFINITY, ssum = 0.0f, acc = 0.0f;

#define ATT_UPDATE(vv)                                                    \
    {                                                                     \
        float tt = (vv) + xr_v;                                           \
        tt = (tt > 0.0f) ? tt : SLOPE * tt;                               \
        float pp = tt * a;                                                \
        pp += __shfl_xor(pp, 1, 16);                                      \
        pp += __shfl_xor(pp, 2, 16);                                      \
        pp += __shfl_xor(pp, 4, 16);                                      \
        pp += __shfl_xor(pp, 8, 16);                                      \
        float nm = fmaxf(m, pp);                                          \
        float eo = __expf(m - nm);                                        \
        float pe = __expf(pp - nm);                                       \
        acc  = acc * eo + pe * (vv);                                      \
        ssum = ssum * eo + pe;                                            \
        m = nm;                                                           \
    }

    int e = e0;
    for (; e + 4 <= e1; e += 4) {
        int j0 = csr[e], j1 = csr[e + 1], j2 = csr[e + 2], j3 = csr[e + 3];
        float v0 = xl[(long)j0 * HID + lane];
        float v1 = xl[(long)j1 * HID + lane];
        float v2 = xl[(long)j2 * HID + lane];
        float v3 = xl[(long)j3 * HID + lane];
        ATT_UPDATE(v0); ATT_UPDATE(v1); ATT_UPDATE(v2); ATT_UPDATE(v3);
    }
    for (; e < e1; ++e) {
        int j = csr[e];
        float v = xl[(long)j * HID + lane];
        ATT_UPDATE(v);
    }
#undef ATT_UPDATE

    float r = acc / (ssum + 1e-16f) + bi + out_un[(long)node * HID + lane];
    out_un[(long)node * HID + lane] = r;

    // LayerNorm partials: wave-reduce sum / sumsq, one double-atomic pair per wave
    float s1 = r, s2 = r * r;
#pragma unroll
    for (int d = 32; d; d >>= 1) {
        s1 += __shfl_xor(s1, d, 64);
        s2 += __shfl_xor(s2, d, 64);
    }
    if (lane == 0) {
        atomicAdd(&red[0], (double)s1);
        atomicAdd(&red[1], (double)s2);
    }
}

// ---------- K7: global LayerNorm finalize ----------
__global__ void ln_kernel(const float* __restrict__ out_un, const double* __restrict__ red,
                          const float* __restrict__ ln_w, const float* __restrict__ ln_b,
                          float* __restrict__ out, int total /* n*HID, mult of 4 */)
{
    double cnt  = (double)total;
    double mu   = red[0] / cnt;
    double var  = red[1] / cnt - mu * mu;
    float mean  = (float)mu;
    float inv   = 1.0f / (sqrtf((float)(var > 0.0 ? var : 0.0)) + LN_EPS);
    int n4 = total >> 2;
    for (int i = blockIdx.x * blockDim.x + threadIdx.x; i < n4; i += gridDim.x * blockDim.x) {
        float4 v = ((const float4*)out_un)[i];
        int cb = (i << 2) & 63;
        float4 r;
        r.x = (v.x - mean) * inv * ln_w[cb + 0] + ln_b[cb + 0];
        r.y = (v.y - mean) * inv * ln_w[cb + 1] + ln_b[cb + 1];
        r.z = (v.z - mean) * inv * ln_w[cb + 2] + ln_b[cb + 2];
        r.w = (v.w - mean) * inv * ln_w[cb + 3] + ln_b[cb + 3];
        ((float4*)out)[i] = r;
    }
}

extern "C" void kernel_launch(void* const* d_in, const int* in_sizes, int n_in,
                              void* d_out, int out_size, void* d_ws, size_t ws_size,
                              hipStream_t stream)
{
    const float* x    = (const float*)d_in[0];
    const int*   ei   = (const int*)d_in[1];
    const float* Wl   = (const float*)d_in[2];
    const float* bl   = (const float*)d_in[3];
    const float* Wr   = (const float*)d_in[4];
    const float* br   = (const float*)d_in[5];
    const float* att  = (const float*)d_in[6];
    const float* bias = (const float*)d_in[7];
    const float* Wres = (const float*)d_in[8];
    const float* lnw  = (const float*)d_in[9];
    const float* lnb  = (const float*)d_in[10];

    int n = in_sizes[0] / IN_DIM;      // 100000
    int e = in_sizes[1] / 2;           // 1600000
    const int* src = ei;
    const int* dst = ei + e;

    // workspace layout (ws re-poisoned every call -> everything re-initialized)
    char* w = (char*)d_ws;
    double* red   = (double*)w;                              // 2 doubles
    float* xl     = (float*)(w + 256);
    float* xr     = xl + (long)n * HID;
    float* out_un = xr + (long)n * HID;                      // res -> row result
    int*   deg    = (int*)(out_un + (long)n * HID);
    int*   off    = deg + n;                                 // n+1
    int*   cursor = off + n + 1;
    int*   csr    = cursor + n;                              // e+n entries

    proj_kernel<<<(n + BM - 1) / BM, 256, 0, stream>>>(x, Wl, bl, Wr, br, Wres,
                                                       xl, xr, out_un, n);

    deg_init_kernel<<<512, 256, 0, stream>>>(deg, n);
    deg_count_kernel<<<4096, 256, 0, stream>>>(dst, deg, e);
    scan_kernel<<<1, 1024, 0, stream>>>(deg, off, cursor, n);
    scatter_kernel<<<4096, 256, 0, stream>>>(src, dst, cursor, csr, e, n);

    init_red_kernel<<<1, 1, 0, stream>>>(red);
    attn_kernel<<<(n + 3) / 4, 256, 0, stream>>>(xl, xr, att, bias, off, csr, out_un, red, n);

    ln_kernel<<<4096, 256, 0, stream>>>(out_un, red, lnw, lnb, (float*)d_out, n * HID);
}

// Round 3
// 577.896 us; speedup vs baseline: 4.9954x; 4.9954x over previous
//
#include <hip/hip_runtime.h>
#include <math.h>

#define SLOPE  0.2f
#define LN_EPS 1e-5f
#define HID    64
#define IN_DIM 128
#define BM     64        // rows per proj block

// ---------- K1: tiled fused projections: xl=x@Wl+bl, xr=x@Wr+br, res=x@Wres ----------
__global__ __launch_bounds__(256) void proj_kernel(
    const float* __restrict__ x,
    const float* __restrict__ Wl, const float* __restrict__ bl,
    const float* __restrict__ Wr, const float* __restrict__ br,
    const float* __restrict__ Wres,
    float* __restrict__ xl, float* __restrict__ xr, float* __restrict__ out_un,
    int n)
{
    __shared__ float xs[BM][132];            // +4 pad
    int t = threadIdx.x;
    int row0 = blockIdx.x * BM;

#pragma unroll
    for (int p = 0; p < 8; ++p) {
        int f  = t + p * 256;
        int r  = f >> 5;                     // 32 float4 per row
        int c4 = f & 31;
        float4 v = make_float4(0.f, 0.f, 0.f, 0.f);
        if (row0 + r < n) v = ((const float4*)x)[(long)(row0 + r) * 32 + c4];
        *(float4*)&xs[r][c4 * 4] = v;
    }
    __syncthreads();

    int cb = (t & 15) * 4;
    int ry = (t >> 4) * 4;

    float4 acc[3][4];
#pragma unroll
    for (int r = 0; r < 4; ++r) {
        acc[0][r] = *(const float4*)&bl[cb];
        acc[1][r] = *(const float4*)&br[cb];
        acc[2][r] = make_float4(0.f, 0.f, 0.f, 0.f);
    }

    for (int k4 = 0; k4 < 32; ++k4) {
        float4 xv[4];
#pragma unroll
        for (int r = 0; r < 4; ++r)
            xv[r] = *(const float4*)&xs[ry + r][k4 * 4];
#pragma unroll
        for (int kk = 0; kk < 4; ++kk) {
            int k = k4 * 4 + kk;
            float4 w0 = *(const float4*)&Wl  [k * HID + cb];
            float4 w1 = *(const float4*)&Wr  [k * HID + cb];
            float4 w2 = *(const float4*)&Wres[k * HID + cb];
#pragma unroll
            for (int r = 0; r < 4; ++r) {
                float xvk = (kk == 0) ? xv[r].x : (kk == 1) ? xv[r].y
                          : (kk == 2) ? xv[r].z : xv[r].w;
                acc[0][r].x = fmaf(xvk, w0.x, acc[0][r].x);
                acc[0][r].y = fmaf(xvk, w0.y, acc[0][r].y);
                acc[0][r].z = fmaf(xvk, w0.z, acc[0][r].z);
                acc[0][r].w = fmaf(xvk, w0.w, acc[0][r].w);
                acc[1][r].x = fmaf(xvk, w1.x, acc[1][r].x);
                acc[1][r].y = fmaf(xvk, w1.y, acc[1][r].y);
                acc[1][r].z = fmaf(xvk, w1.z, acc[1][r].z);
                acc[1][r].w = fmaf(xvk, w1.w, acc[1][r].w);
                acc[2][r].x = fmaf(xvk, w2.x, acc[2][r].x);
                acc[2][r].y = fmaf(xvk, w2.y, acc[2][r].y);
                acc[2][r].z = fmaf(xvk, w2.z, acc[2][r].z);
                acc[2][r].w = fmaf(xvk, w2.w, acc[2][r].w);
            }
        }
    }

#pragma unroll
    for (int r = 0; r < 4; ++r) {
        long ro = row0 + ry + r;
        if (ro < n) {
            *(float4*)&xl    [ro * HID + cb] = acc[0][r];
            *(float4*)&xr    [ro * HID + cb] = acc[1][r];
            *(float4*)&out_un[ro * HID + cb] = acc[2][r];
        }
    }
}

// ---------- K2: degree init (self-loop counts as 1) ----------
__global__ void deg_init_kernel(int* __restrict__ deg, int n) {
    for (int i = blockIdx.x * blockDim.x + threadIdx.x; i < n; i += gridDim.x * blockDim.x)
        deg[i] = 1;
}

// ---------- K3: degree histogram over real edges ----------
__global__ void deg_count_kernel(const int* __restrict__ dst, int* __restrict__ deg, int e) {
    for (int i = blockIdx.x * blockDim.x + threadIdx.x; i < e; i += gridDim.x * blockDim.x)
        atomicAdd(&deg[dst[i]], 1);
}

// ---------- K4: single-block exclusive scan, int4 per thread ----------
__global__ __launch_bounds__(1024) void scan_kernel(
    const int* __restrict__ deg, int* __restrict__ off, int* __restrict__ cursor, int n)
{
    __shared__ int wsum[16];
    __shared__ int carry_s;
    int t = threadIdx.x, lane = t & 63, w = t >> 6;
    if (t == 0) carry_s = 0;
    __syncthreads();
    for (int base = 0; base < n; base += 4096) {
        int i0 = base + t * 4;
        int4 v = make_int4(0, 0, 0, 0);
        if (i0 + 3 < n)      v = *(const int4*)&deg[i0];
        else if (i0 < n) {
            v.x = deg[i0];
            if (i0 + 1 < n) v.y = deg[i0 + 1];
            if (i0 + 2 < n) v.z = deg[i0 + 2];
        }
        int local = v.x + v.y + v.z + v.w;
        int inc = local;
#pragma unroll
        for (int d = 1; d < 64; d <<= 1) {
            int o = __shfl_up(inc, d, 64);
            if (lane >= d) inc += o;
        }
        if (lane == 63) wsum[w] = inc;
        __syncthreads();
        if (w == 0 && lane < 16) {
            int s = wsum[lane];
#pragma unroll
            for (int d = 1; d < 16; d <<= 1) {
                int o = __shfl_up(s, d, 16);
                if (lane >= d) s += o;
            }
            wsum[lane] = s;
        }
        __syncthreads();
        int woff = (w > 0) ? wsum[w - 1] : 0;
        int bc = carry_s;
        __syncthreads();
        int o0 = bc + woff + inc - local;
        int o1 = o0 + v.x, o2 = o1 + v.y, o3 = o2 + v.z;
        if (i0     < n) { off[i0]     = o0; cursor[i0]     = o0; }
        if (i0 + 1 < n) { off[i0 + 1] = o1; cursor[i0 + 1] = o1; }
        if (i0 + 2 < n) { off[i0 + 2] = o2; cursor[i0 + 2] = o2; }
        if (i0 + 3 < n) { off[i0 + 3] = o3; cursor[i0 + 3] = o3; }
        if (t == 1023) carry_s = bc + wsum[15];
        __syncthreads();
    }
    if (threadIdx.x == 0) off[n] = carry_s;
}

// ---------- K5: scatter edges (and self-loops) into CSR by dst ----------
__global__ void scatter_kernel(const int* __restrict__ src, const int* __restrict__ dst,
                               int* __restrict__ cursor, int* __restrict__ csr,
                               int e, int n)
{
    int total = e + n;
    for (int i = blockIdx.x * blockDim.x + threadIdx.x; i < total; i += gridDim.x * blockDim.x) {
        int d, s;
        if (i < e) { d = dst[i]; s = src[i]; }
        else       { d = i - e;  s = i - e; }   // self-loop
        int p = atomicAdd(&cursor[d], 1);
        csr[p] = s;
    }
}

__global__ void init_red_kernel(double* red) {
    red[0] = 0.0; red[1] = 0.0;
}

// ---------- K6: per-node attention, one wave per node; NO global atomics ----------
__global__ __launch_bounds__(256) void attn_kernel(
    const float* __restrict__ xl, const float* __restrict__ xr,
    const float* __restrict__ att, const float* __restrict__ bias,
    const int* __restrict__ off, const int* __restrict__ csr,
    float* __restrict__ out_un,   // holds x@W_res on entry; overwritten with row result
    float2* __restrict__ partials, int n)
{
    int lane = threadIdx.x & 63;
    int wid  = threadIdx.x >> 6;
    int node = blockIdx.x * 4 + wid;

    float s1 = 0.0f, s2 = 0.0f;
    if (node < n) {
        float a    = att[lane];
        float bi   = bias[lane];
        float xr_v = xr[(long)node * HID + lane];

        int e0 = off[node], e1 = off[node + 1];

        float m = -INFINITY, ssum = 0.0f, acc = 0.0f;

#define ATT_UPDATE(vv)                                                    \
        {                                                                 \
            float tt = (vv) + xr_v;                                       \
            tt = (tt > 0.0f) ? tt : SLOPE * tt;                           \
            float pp = tt * a;                                            \
            pp += __shfl_xor(pp, 1, 16);                                  \
            pp += __shfl_xor(pp, 2, 16);                                  \
            pp += __shfl_xor(pp, 4, 16);                                  \
            pp += __shfl_xor(pp, 8, 16);                                  \
            float nm = fmaxf(m, pp);                                      \
            float eo = __expf(m - nm);                                    \
            float pe = __expf(pp - nm);                                   \
            acc  = acc * eo + pe * (vv);                                  \
            ssum = ssum * eo + pe;                                        \
            m = nm;                                                       \
        }

        int e = e0;
        for (; e + 4 <= e1; e += 4) {
            int j0 = csr[e], j1 = csr[e + 1], j2 = csr[e + 2], j3 = csr[e + 3];
            float v0 = xl[(long)j0 * HID + lane];
            float v1 = xl[(long)j1 * HID + lane];
            float v2 = xl[(long)j2 * HID + lane];
            float v3 = xl[(long)j3 * HID + lane];
            ATT_UPDATE(v0); ATT_UPDATE(v1); ATT_UPDATE(v2); ATT_UPDATE(v3);
        }
        for (; e < e1; ++e) {
            int j = csr[e];
            float v = xl[(long)j * HID + lane];
            ATT_UPDATE(v);
        }
#undef ATT_UPDATE

        float r = acc / (ssum + 1e-16f) + bi + out_un[(long)node * HID + lane];
        out_un[(long)node * HID + lane] = r;
        s1 = r; s2 = r * r;
    }

    // wave reduce, then block reduce via LDS -> one plain store per block
#pragma unroll
    for (int d = 32; d; d >>= 1) {
        s1 += __shfl_xor(s1, d, 64);
        s2 += __shfl_xor(s2, d, 64);
    }
    __shared__ float bs[8];
    if (lane == 0) { bs[wid] = s1; bs[4 + wid] = s2; }
    __syncthreads();
    if (threadIdx.x == 0)
        partials[blockIdx.x] = make_float2(bs[0] + bs[1] + bs[2] + bs[3],
                                           bs[4] + bs[5] + bs[6] + bs[7]);
}

// ---------- K6b: reduce per-block partials into red[0..1] (few atomics) ----------
__global__ __launch_bounds__(256) void reduce_kernel(
    const float2* __restrict__ partials, double* __restrict__ red, int nb)
{
    double a = 0.0, b = 0.0;
    for (int i = blockIdx.x * blockDim.x + threadIdx.x; i < nb; i += gridDim.x * blockDim.x) {
        float2 p = partials[i];
        a += (double)p.x; b += (double)p.y;
    }
#pragma unroll
    for (int d = 32; d; d >>= 1) {
        a += __shfl_xor(a, d, 64);
        b += __shfl_xor(b, d, 64);
    }
    if ((threadIdx.x & 63) == 0) {
        atomicAdd(&red[0], a);
        atomicAdd(&red[1], b);
    }
}

// ---------- K7: global LayerNorm finalize ----------
__global__ void ln_kernel(const float* __restrict__ out_un, const double* __restrict__ red,
                          const float* __restrict__ ln_w, const float* __restrict__ ln_b,
                          float* __restrict__ out, int total /* n*HID, mult of 4 */)
{
    double cnt  = (double)total;
    double mu   = red[0] / cnt;
    double var  = red[1] / cnt - mu * mu;
    float mean  = (float)mu;
    float inv   = 1.0f / (sqrtf((float)(var > 0.0 ? var : 0.0)) + LN_EPS);
    int n4 = total >> 2;
    for (int i = blockIdx.x * blockDim.x + threadIdx.x; i < n4; i += gridDim.x * blockDim.x) {
        float4 v = ((const float4*)out_un)[i];
        int cb = (i << 2) & 63;
        float4 r;
        r.x = (v.x - mean) * inv * ln_w[cb + 0] + ln_b[cb + 0];
        r.y = (v.y - mean) * inv * ln_w[cb + 1] + ln_b[cb + 1];
        r.z = (v.z - mean) * inv * ln_w[cb + 2] + ln_b[cb + 2];
        r.w = (v.w - mean) * inv * ln_w[cb + 3] + ln_b[cb + 3];
        ((float4*)out)[i] = r;
    }
}

extern "C" void kernel_launch(void* const* d_in, const int* in_sizes, int n_in,
                              void* d_out, int out_size, void* d_ws, size_t ws_size,
                              hipStream_t stream)
{
    const float* x    = (const float*)d_in[0];
    const int*   ei   = (const int*)d_in[1];
    const float* Wl   = (const float*)d_in[2];
    const float* bl   = (const float*)d_in[3];
    const float* Wr   = (const float*)d_in[4];
    const float* br   = (const float*)d_in[5];
    const float* att  = (const float*)d_in[6];
    const float* bias = (const float*)d_in[7];
    const float* Wres = (const float*)d_in[8];
    const float* lnw  = (const float*)d_in[9];
    const float* lnb  = (const float*)d_in[10];

    int n = in_sizes[0] / IN_DIM;      // 100000
    int e = in_sizes[1] / 2;           // 1600000
    const int* src = ei;
    const int* dst = ei + e;

    int nblocks = (n + 3) / 4;

    // workspace layout (ws re-poisoned every call -> everything re-initialized)
    char* w = (char*)d_ws;
    double* red    = (double*)w;                              // 2 doubles
    float* xl      = (float*)(w + 256);
    float* xr      = xl + (long)n * HID;
    float* out_un  = xr + (long)n * HID;                      // res -> row result
    int*   deg     = (int*)(out_un + (long)n * HID);
    int*   off     = deg + n;                                 // n+1
    int*   cursor  = off + n + 1;
    int*   csr     = cursor + n;                              // e+n entries
    float2* partials = (float2*)(csr + e + n);                // nblocks float2

    proj_kernel<<<(n + BM - 1) / BM, 256, 0, stream>>>(x, Wl, bl, Wr, br, Wres,
                                                       xl, xr, out_un, n);

    deg_init_kernel<<<512, 256, 0, stream>>>(deg, n);
    deg_count_kernel<<<4096, 256, 0, stream>>>(dst, deg, e);
    scan_kernel<<<1, 1024, 0, stream>>>(deg, off, cursor, n);
    scatter_kernel<<<4096, 256, 0, stream>>>(src, dst, cursor, csr, e, n);

    init_red_kernel<<<1, 1, 0, stream>>>(red);
    attn_kernel<<<nblocks, 256, 0, stream>>>(xl, xr, att, bias, off, csr,
                                             out_un, partials, n);
    reduce_kernel<<<64, 256, 0, stream>>>(partials, red, nblocks);

    ln_kernel<<<4096, 256, 0, stream>>>(out_un, red, lnw, lnb, (float*)d_out, n * HID);
}

// Round 4
// 462.794 us; speedup vs baseline: 6.2378x; 1.2487x over previous
//
#include <hip/hip_runtime.h>
#include <math.h>

#define SLOPE  0.2f
#define LN_EPS 1e-5f
#define HID    64
#define IN_DIM 128
#define BM     64        // rows per proj block

// ---------- K1: tiled fused projections: xl=x@Wl+bl, xr=x@Wr+br, res=x@Wres ----------
__global__ __launch_bounds__(256) void proj_kernel(
    const float* __restrict__ x,
    const float* __restrict__ Wl, const float* __restrict__ bl,
    const float* __restrict__ Wr, const float* __restrict__ br,
    const float* __restrict__ Wres,
    float* __restrict__ xl, float* __restrict__ xr, float* __restrict__ out_un,
    int n)
{
    __shared__ float xs[BM][132];            // +4 pad
    int t = threadIdx.x;
    int row0 = blockIdx.x * BM;

#pragma unroll
    for (int p = 0; p < 8; ++p) {
        int f  = t + p * 256;
        int r  = f >> 5;                     // 32 float4 per row
        int c4 = f & 31;
        float4 v = make_float4(0.f, 0.f, 0.f, 0.f);
        if (row0 + r < n) v = ((const float4*)x)[(long)(row0 + r) * 32 + c4];
        *(float4*)&xs[r][c4 * 4] = v;
    }
    __syncthreads();

    int cb = (t & 15) * 4;
    int ry = (t >> 4) * 4;

    float4 acc[3][4];
#pragma unroll
    for (int r = 0; r < 4; ++r) {
        acc[0][r] = *(const float4*)&bl[cb];
        acc[1][r] = *(const float4*)&br[cb];
        acc[2][r] = make_float4(0.f, 0.f, 0.f, 0.f);
    }

    for (int k4 = 0; k4 < 32; ++k4) {
        float4 xv[4];
#pragma unroll
        for (int r = 0; r < 4; ++r)
            xv[r] = *(const float4*)&xs[ry + r][k4 * 4];
#pragma unroll
        for (int kk = 0; kk < 4; ++kk) {
            int k = k4 * 4 + kk;
            float4 w0 = *(const float4*)&Wl  [k * HID + cb];
            float4 w1 = *(const float4*)&Wr  [k * HID + cb];
            float4 w2 = *(const float4*)&Wres[k * HID + cb];
#pragma unroll
            for (int r = 0; r < 4; ++r) {
                float xvk = (kk == 0) ? xv[r].x : (kk == 1) ? xv[r].y
                          : (kk == 2) ? xv[r].z : xv[r].w;
                acc[0][r].x = fmaf(xvk, w0.x, acc[0][r].x);
                acc[0][r].y = fmaf(xvk, w0.y, acc[0][r].y);
                acc[0][r].z = fmaf(xvk, w0.z, acc[0][r].z);
                acc[0][r].w = fmaf(xvk, w0.w, acc[0][r].w);
                acc[1][r].x = fmaf(xvk, w1.x, acc[1][r].x);
                acc[1][r].y = fmaf(xvk, w1.y, acc[1][r].y);
                acc[1][r].z = fmaf(xvk, w1.z, acc[1][r].z);
                acc[1][r].w = fmaf(xvk, w1.w, acc[1][r].w);
                acc[2][r].x = fmaf(xvk, w2.x, acc[2][r].x);
                acc[2][r].y = fmaf(xvk, w2.y, acc[2][r].y);
                acc[2][r].z = fmaf(xvk, w2.z, acc[2][r].z);
                acc[2][r].w = fmaf(xvk, w2.w, acc[2][r].w);
            }
        }
    }

#pragma unroll
    for (int r = 0; r < 4; ++r) {
        long ro = row0 + ry + r;
        if (ro < n) {
            *(float4*)&xl    [ro * HID + cb] = acc[0][r];
            *(float4*)&xr    [ro * HID + cb] = acc[1][r];
            *(float4*)&out_un[ro * HID + cb] = acc[2][r];
        }
    }
}

// ---------- K2: zero degree array ----------
__global__ void deg_zero_kernel(int* __restrict__ deg, int n) {
    for (int i = blockIdx.x * blockDim.x + threadIdx.x; i < n; i += gridDim.x * blockDim.x)
        deg[i] = 0;
}

// ---------- K3: rank assignment: rank[i] = old count of dst[i]; 4-wide ILP ----------
__global__ __launch_bounds__(256) void rank_kernel(
    const int* __restrict__ dst, int* __restrict__ deg, int* __restrict__ rank, int e)
{
    int tid = blockIdx.x * blockDim.x + threadIdx.x;
    int stride = gridDim.x * blockDim.x;
    int e4 = e >> 2;
    for (int i = tid; i < e4; i += stride) {
        int4 d = ((const int4*)dst)[i];
        int r0 = atomicAdd(&deg[d.x], 1);
        int r1 = atomicAdd(&deg[d.y], 1);
        int r2 = atomicAdd(&deg[d.z], 1);
        int r3 = atomicAdd(&deg[d.w], 1);
        ((int4*)rank)[i] = make_int4(r0, r1, r2, r3);
    }
    for (int i = (e4 << 2) + tid; i < e; i += stride)
        rank[i] = atomicAdd(&deg[dst[i]], 1);
}

// ---------- K4: single-block exclusive scan of (deg[i]+1), int4 per thread ----------
__global__ __launch_bounds__(1024) void scan_kernel(
    const int* __restrict__ deg, int* __restrict__ off, int n)
{
    __shared__ int wsum[16];
    __shared__ int carry_s;
    int t = threadIdx.x, lane = t & 63, w = t >> 6;
    if (t == 0) carry_s = 0;
    __syncthreads();
    for (int base = 0; base < n; base += 4096) {
        int i0 = base + t * 4;
        int4 v = make_int4(0, 0, 0, 0);
        if (i0 + 3 < n) {
            int4 dv = *(const int4*)&deg[i0];
            v = make_int4(dv.x + 1, dv.y + 1, dv.z + 1, dv.w + 1);
        } else if (i0 < n) {
            v.x = deg[i0] + 1;
            if (i0 + 1 < n) v.y = deg[i0 + 1] + 1;
            if (i0 + 2 < n) v.z = deg[i0 + 2] + 1;
        }
        int local = v.x + v.y + v.z + v.w;
        int inc = local;
#pragma unroll
        for (int d = 1; d < 64; d <<= 1) {
            int o = __shfl_up(inc, d, 64);
            if (lane >= d) inc += o;
        }
        if (lane == 63) wsum[w] = inc;
        __syncthreads();
        if (w == 0 && lane < 16) {
            int s = wsum[lane];
#pragma unroll
            for (int d = 1; d < 16; d <<= 1) {
                int o = __shfl_up(s, d, 16);
                if (lane >= d) s += o;
            }
            wsum[lane] = s;
        }
        __syncthreads();
        int woff = (w > 0) ? wsum[w - 1] : 0;
        int bc = carry_s;
        __syncthreads();
        int o0 = bc + woff + inc - local;
        int o1 = o0 + v.x, o2 = o1 + v.y, o3 = o2 + v.z;
        if (i0     < n) off[i0]     = o0;
        if (i0 + 1 < n) off[i0 + 1] = o1;
        if (i0 + 2 < n) off[i0 + 2] = o2;
        if (i0 + 3 < n) off[i0 + 3] = o3;
        if (t == 1023) carry_s = bc + wsum[15];
        __syncthreads();
    }
    if (threadIdx.x == 0) off[n] = carry_s;
}

// ---------- K5: place edges — NO atomics, 4 independent gather+scatter chains ----------
__global__ __launch_bounds__(256) void place_kernel(
    const int* __restrict__ src, const int* __restrict__ dst,
    const int* __restrict__ rank, const int* __restrict__ off,
    int* __restrict__ csr, int e)
{
    int tid = blockIdx.x * blockDim.x + threadIdx.x;
    int stride = gridDim.x * blockDim.x;
    int e4 = e >> 2;
    for (int i = tid; i < e4; i += stride) {
        int4 d = ((const int4*)dst)[i];
        int4 s = ((const int4*)src)[i];
        int4 r = ((const int4*)rank)[i];
        int o0 = off[d.x], o1 = off[d.y], o2 = off[d.z], o3 = off[d.w];
        csr[o0 + r.x] = s.x;
        csr[o1 + r.y] = s.y;
        csr[o2 + r.z] = s.z;
        csr[o3 + r.w] = s.w;
    }
    for (int i = (e4 << 2) + tid; i < e; i += stride)
        csr[off[dst[i]] + rank[i]] = src[i];
}

// ---------- K5b: self-loops take the last slot of each node ----------
__global__ void selfloop_kernel(const int* __restrict__ off, const int* __restrict__ deg,
                                int* __restrict__ csr, int n)
{
    for (int i = blockIdx.x * blockDim.x + threadIdx.x; i < n; i += gridDim.x * blockDim.x)
        csr[off[i] + deg[i]] = i;
}

// ---------- K6: per-node attention, one wave per node; NO global atomics ----------
__global__ __launch_bounds__(256) void attn_kernel(
    const float* __restrict__ xl, const float* __restrict__ xr,
    const float* __restrict__ att, const float* __restrict__ bias,
    const int* __restrict__ off, const int* __restrict__ csr,
    float* __restrict__ out_un,   // holds x@W_res on entry; overwritten with row result
    float2* __restrict__ partials, int n)
{
    int lane = threadIdx.x & 63;
    int wid  = threadIdx.x >> 6;
    int node = blockIdx.x * 4 + wid;

    float s1 = 0.0f, s2 = 0.0f;
    if (node < n) {
        float a    = att[lane];
        float bi   = bias[lane];
        float xr_v = xr[(long)node * HID + lane];

        int e0 = off[node], e1 = off[node + 1];

        float m = -INFINITY, ssum = 0.0f, acc = 0.0f;

#define ATT_UPDATE(vv)                                                    \
        {                                                                 \
            float tt = (vv) + xr_v;                                       \
            tt = (tt > 0.0f) ? tt : SLOPE * tt;                           \
            float pp = tt * a;                                            \
            pp += __shfl_xor(pp, 1, 16);                                  \
            pp += __shfl_xor(pp, 2, 16);                                  \
            pp += __shfl_xor(pp, 4, 16);                                  \
            pp += __shfl_xor(pp, 8, 16);                                  \
            float nm = fmaxf(m, pp);                                      \
            float eo = __expf(m - nm);                                    \
            float pe = __expf(pp - nm);                                   \
            acc  = acc * eo + pe * (vv);                                  \
            ssum = ssum * eo + pe;                                        \
            m = nm;                                                       \
        }

        int e = e0;
        for (; e + 4 <= e1; e += 4) {
            int j0 = csr[e], j1 = csr[e + 1], j2 = csr[e + 2], j3 = csr[e + 3];
            float v0 = xl[(long)j0 * HID + lane];
            float v1 = xl[(long)j1 * HID + lane];
            float v2 = xl[(long)j2 * HID + lane];
            float v3 = xl[(long)j3 * HID + lane];
            ATT_UPDATE(v0); ATT_UPDATE(v1); ATT_UPDATE(v2); ATT_UPDATE(v3);
        }
        for (; e < e1; ++e) {
            int j = csr[e];
            float v = xl[(long)j * HID + lane];
            ATT_UPDATE(v);
        }
#undef ATT_UPDATE

        float r = acc / (ssum + 1e-16f) + bi + out_un[(long)node * HID + lane];
        out_un[(long)node * HID + lane] = r;
        s1 = r; s2 = r * r;
    }

    // wave reduce, then block reduce via LDS -> one plain store per block
#pragma unroll
    for (int d = 32; d; d >>= 1) {
        s1 += __shfl_xor(s1, d, 64);
        s2 += __shfl_xor(s2, d, 64);
    }
    __shared__ float bs[8];
    if (lane == 0) { bs[wid] = s1; bs[4 + wid] = s2; }
    __syncthreads();
    if (threadIdx.x == 0)
        partials[blockIdx.x] = make_float2(bs[0] + bs[1] + bs[2] + bs[3],
                                           bs[4] + bs[5] + bs[6] + bs[7]);
}

// ---------- K6b: single-block reduction of partials -> red (no atomics, no init) ----------
__global__ __launch_bounds__(1024) void reduce_kernel(
    const float2* __restrict__ partials, double* __restrict__ red, int nb)
{
    double a = 0.0, b = 0.0;
    for (int i = threadIdx.x; i < nb; i += 1024) {
        float2 p = partials[i];
        a += (double)p.x; b += (double)p.y;
    }
#pragma unroll
    for (int d = 32; d; d >>= 1) {
        a += __shfl_xor(a, d, 64);
        b += __shfl_xor(b, d, 64);
    }
    __shared__ double sa[16], sb[16];
    int w = threadIdx.x >> 6;
    if ((threadIdx.x & 63) == 0) { sa[w] = a; sb[w] = b; }
    __syncthreads();
    if (threadIdx.x == 0) {
        double ta = 0.0, tb = 0.0;
#pragma unroll
        for (int k = 0; k < 16; ++k) { ta += sa[k]; tb += sb[k]; }
        red[0] = ta; red[1] = tb;
    }
}

// ---------- K7: global LayerNorm finalize ----------
__global__ void ln_kernel(const float* __restrict__ out_un, const double* __restrict__ red,
                          const float* __restrict__ ln_w, const float* __restrict__ ln_b,
                          float* __restrict__ out, int total /* n*HID, mult of 4 */)
{
    double cnt  = (double)total;
    double mu   = red[0] / cnt;
    double var  = red[1] / cnt - mu * mu;
    float mean  = (float)mu;
    float inv   = 1.0f / (sqrtf((float)(var > 0.0 ? var : 0.0)) + LN_EPS);
    int n4 = total >> 2;
    for (int i = blockIdx.x * blockDim.x + threadIdx.x; i < n4; i += gridDim.x * blockDim.x) {
        float4 v = ((const float4*)out_un)[i];
        int cb = (i << 2) & 63;
        float4 r;
        r.x = (v.x - mean) * inv * ln_w[cb + 0] + ln_b[cb + 0];
        r.y = (v.y - mean) * inv * ln_w[cb + 1] + ln_b[cb + 1];
        r.z = (v.z - mean) * inv * ln_w[cb + 2] + ln_b[cb + 2];
        r.w = (v.w - mean) * inv * ln_w[cb + 3] + ln_b[cb + 3];
        ((float4*)out)[i] = r;
    }
}

extern "C" void kernel_launch(void* const* d_in, const int* in_sizes, int n_in,
                              void* d_out, int out_size, void* d_ws, size_t ws_size,
                              hipStream_t stream)
{
    const float* x    = (const float*)d_in[0];
    const int*   ei   = (const int*)d_in[1];
    const float* Wl   = (const float*)d_in[2];
    const float* bl   = (const float*)d_in[3];
    const float* Wr   = (const float*)d_in[4];
    const float* br   = (const float*)d_in[5];
    const float* att  = (const float*)d_in[6];
    const float* bias = (const float*)d_in[7];
    const float* Wres = (const float*)d_in[8];
    const float* lnw  = (const float*)d_in[9];
    const float* lnb  = (const float*)d_in[10];

    int n = in_sizes[0] / IN_DIM;      // 100000
    int e = in_sizes[1] / 2;           // 1600000
    const int* src = ei;
    const int* dst = ei + e;

    int nblocks = (n + 3) / 4;

    // workspace layout (ws re-poisoned every call -> everything re-initialized)
    // NOTE lifetimes: rank aliases out_un (dead once place_kernel finishes; proj runs
    // after and overwrites). partials aliases deg (dead once selfloop_kernel finishes).
    char* w = (char*)d_ws;
    double* red    = (double*)w;                              // 2 doubles
    float* xl      = (float*)(w + 256);
    float* xr      = xl + (long)n * HID;
    float* out_un  = xr + (long)n * HID;                      // rank -> res -> row result
    int*   deg     = (int*)(out_un + (long)n * HID);          // also partials later
    int*   off     = deg + n;                                 // n+1
    int*   csr     = off + n + 1;                             // e+n entries
    int*    rank     = (int*)out_un;                          // alias (e ints <= n*HID floats)
    float2* partials = (float2*)deg;                          // alias (nblocks*8B <= n*4B)

    // ---- CSR build (before proj, since rank aliases out_un) ----
    deg_zero_kernel<<<512, 256, 0, stream>>>(deg, n);
    rank_kernel<<<1024, 256, 0, stream>>>(dst, deg, rank, e);
    scan_kernel<<<1, 1024, 0, stream>>>(deg, off, n);
    place_kernel<<<1024, 256, 0, stream>>>(src, dst, rank, off, csr, e);
    selfloop_kernel<<<512, 256, 0, stream>>>(off, deg, csr, n);

    // ---- projections ----
    proj_kernel<<<(n + BM - 1) / BM, 256, 0, stream>>>(x, Wl, bl, Wr, br, Wres,
                                                       xl, xr, out_un, n);

    // ---- attention + residual + LN stats ----
    attn_kernel<<<nblocks, 256, 0, stream>>>(xl, xr, att, bias, off, csr,
                                             out_un, partials, n);
    reduce_kernel<<<1, 1024, 0, stream>>>(partials, red, nblocks);

    ln_kernel<<<4096, 256, 0, stream>>>(out_un, red, lnw, lnb, (float*)d_out, n * HID);
}